// Round 1
// baseline (113.646 us; speedup 1.0000x reference)
//
#include <hip/hip_runtime.h>
#include <math.h>

#define BDIM 4
#define DIM 512
#define TT 2048
#define CDIM 14
#define NTOK (BDIM * TT)              // 8192 tokens
#define NB 16384                      // 2^14 codes
#define OUT_ELEMS (BDIM * DIM * TT)   // 4194304
#define FEPS 1e-20f

// ---------------------------------------------------------------------------
// Kernel 1: h = x^T W_in^T + b_in  (per token, 14 dims), then per-token tail:
//   indices, commitment, per-sample entropy (factorized binary entropies),
//   sparse histogram accumulation (softmax over 16384 codes factorizes into
//   14 Bernoullis; only "soft" bits (p not exactly 0/1 in f32) branch).
// Grid: 256 blocks x 256 threads; block = 32 tokens x 8 d-groups of 64.
// ---------------------------------------------------------------------------
__global__ __launch_bounds__(256) void k_proj_in(
    const float* __restrict__ x,
    const float* __restrict__ W_in,
    const float* __restrict__ b_in,
    float* __restrict__ out_idx,      // [8192] indices stored as float
    float* __restrict__ hist,         // [16384] zeroed before launch
    float* __restrict__ pse_part,     // [256]
    float* __restrict__ commit_part)  // [256]
{
    __shared__ float Wl[DIM][16];      // W_in transposed, padded 14->16 (32KB)
    __shared__ float red[8][32][14];   // partial-h reduction (14KB)

    const int tid = threadIdx.x;

    // stage W_in[c][d] -> Wl[d][c]
    for (int i = tid; i < CDIM * DIM; i += 256) {
        const int c = i >> 9;        // / 512
        const int d = i & (DIM - 1); // % 512
        Wl[d][c] = W_in[i];
    }
    __syncthreads();

    const int t_local = tid & 31;
    const int dg = tid >> 5;                       // 0..7
    const int tg = blockIdx.x * 32 + t_local;      // global token id
    const int b = tg >> 11;
    const int t = tg & (TT - 1);

    const float* xp = x + ((size_t)(b * DIM + dg * 64)) * TT + t;

    float acc[14];
#pragma unroll
    for (int c = 0; c < 14; ++c) acc[c] = 0.f;

#pragma unroll 8
    for (int i = 0; i < 64; ++i) {
        const float xv = xp[(size_t)i * TT];          // coalesced over lanes (t)
        const float4* wr = (const float4*)(&Wl[dg * 64 + i][0]);
        const float4 w0 = wr[0];
        const float4 w1 = wr[1];
        const float4 w2 = wr[2];
        const float2 w3 = ((const float2*)wr)[6];     // floats 12,13
        acc[0]  = fmaf(xv, w0.x, acc[0]);
        acc[1]  = fmaf(xv, w0.y, acc[1]);
        acc[2]  = fmaf(xv, w0.z, acc[2]);
        acc[3]  = fmaf(xv, w0.w, acc[3]);
        acc[4]  = fmaf(xv, w1.x, acc[4]);
        acc[5]  = fmaf(xv, w1.y, acc[5]);
        acc[6]  = fmaf(xv, w1.z, acc[6]);
        acc[7]  = fmaf(xv, w1.w, acc[7]);
        acc[8]  = fmaf(xv, w2.x, acc[8]);
        acc[9]  = fmaf(xv, w2.y, acc[9]);
        acc[10] = fmaf(xv, w2.z, acc[10]);
        acc[11] = fmaf(xv, w2.w, acc[11]);
        acc[12] = fmaf(xv, w3.x, acc[12]);
        acc[13] = fmaf(xv, w3.y, acc[13]);
    }

#pragma unroll
    for (int c = 0; c < 14; ++c) red[dg][t_local][c] = acc[c];
    __syncthreads();

    float pse = 0.f, commit = 0.f;
    if (tid < 32) {
        // finish h for token (blockIdx*32 + tid)
        float h[14];
#pragma unroll
        for (int c = 0; c < 14; ++c) {
            float s = b_in[c];
#pragma unroll
            for (int g = 0; g < 8; ++g) s += red[g][tid][c];
            h[c] = s;
        }

        unsigned int idx = 0;
        float p[14];
#pragma unroll
        for (int c = 0; c < 14; ++c) {
            const float hc = h[c];
            const bool pos = hc > 0.f;
            if (pos) idx |= (1u << (13 - c));
            const float sgn = pos ? 1.f : -1.f;
            const float dlt = hc - sgn;
            commit += dlt * dlt;
            const float pc = 1.f / (1.f + expf(-400.f * hc)); // sigmoid(2*inv_temp*2*scale*h)
            p[c] = pc;
            const float qc = 1.f - pc;
            pse -= pc * logf(fmaxf(pc, FEPS)) + qc * logf(fmaxf(qc, FEPS));
        }
        out_idx[blockIdx.x * 32 + tid] = (float)idx;

        // sparse histogram: enumerate subsets over "soft" bits only
        unsigned int base = 0;
        int nsoft = 0;
        int softbit[14];
        float softp[14];
#pragma unroll
        for (int c = 0; c < 14; ++c) {
            if (p[c] == 1.f) {
                base |= (1u << (13 - c));
            } else if (p[c] != 0.f) {
                softbit[nsoft] = 13 - c;
                softp[nsoft] = p[c];
                ++nsoft;
            }
        }
        const int nsub = 1 << nsoft;
        for (int m = 0; m < nsub; ++m) {
            float pr = 1.f;
            unsigned int code = base;
            for (int j = 0; j < nsoft; ++j) {
                if (m & (1 << j)) { pr *= softp[j]; code |= (1u << softbit[j]); }
                else              { pr *= (1.f - softp[j]); }
            }
            atomicAdd(hist + code, pr);
        }
    }

    // deterministic per-block partials for pse/commit
    __syncthreads();
    float* sc = (float*)red;   // reuse LDS
    if (tid < 32) { sc[tid] = pse; sc[32 + tid] = commit; }
    __syncthreads();
    if (tid == 0) {
        float ps = 0.f, cm = 0.f;
        for (int i = 0; i < 32; ++i) { ps += sc[i]; cm += sc[32 + i]; }
        pse_part[blockIdx.x] = ps;
        commit_part[blockIdx.x] = cm;
    }
}

// ---------------------------------------------------------------------------
// Kernel 2: out[b][d][t] = sum_c sign_c * W_out[d][c] + b_out[d]
// One thread per output element; d,b are block-uniform -> scalar W_out loads.
// ---------------------------------------------------------------------------
__global__ __launch_bounds__(256) void k_proj_out(
    const float* __restrict__ idxf,
    const float* __restrict__ W_out,
    const float* __restrict__ b_out,
    float* __restrict__ out)
{
    const int base = blockIdx.x * 256;
    const int b = base >> 20;                 // / (512*2048)
    const int d = (base >> 11) & (DIM - 1);
    const int t = (base & (TT - 1)) + threadIdx.x;
    const unsigned int u = (unsigned int)idxf[b * TT + t];
    float s = b_out[d];
#pragma unroll
    for (int c = 0; c < 14; ++c) {
        const float w = W_out[d * 14 + c];
        s += (u & (1u << (13 - c))) ? w : -w;
    }
    out[base + threadIdx.x] = s;
}

// ---------------------------------------------------------------------------
// Kernel 3: codebook entropy from histogram + combine partials -> aux scalar
// ---------------------------------------------------------------------------
__global__ __launch_bounds__(256) void k_finalize(
    const float* __restrict__ hist,
    const float* __restrict__ pse_part,
    const float* __restrict__ commit_part,
    float* __restrict__ aux_out)
{
    __shared__ float sred[256];
    const int tid = threadIdx.x;

    float ce = 0.f;
    for (int j = tid; j < NB; j += 256) {
        const float a = hist[j] * (1.f / (float)NTOK);
        if (a > 0.f) ce -= a * logf(fmaxf(a, FEPS));
    }
    const float ps = pse_part[tid];
    const float cm = commit_part[tid];

    sred[tid] = ce; __syncthreads();
    for (int s = 128; s > 0; s >>= 1) { if (tid < s) sred[tid] += sred[tid + s]; __syncthreads(); }
    const float ce_sum = sred[0]; __syncthreads();

    sred[tid] = ps; __syncthreads();
    for (int s = 128; s > 0; s >>= 1) { if (tid < s) sred[tid] += sred[tid + s]; __syncthreads(); }
    const float ps_sum = sred[0]; __syncthreads();

    sred[tid] = cm; __syncthreads();
    for (int s = 128; s > 0; s >>= 1) { if (tid < s) sred[tid] += sred[tid + s]; __syncthreads(); }
    const float cm_sum = sred[0];

    if (tid == 0) {
        const float per_sample = ps_sum * (1.f / (float)NTOK);
        const float commit = cm_sum * (1.f / ((float)NTOK * (float)CDIM));
        // aux = (per_sample_entropy - gamma*codebook_entropy)*0.1 + commit*1.0
        aux_out[0] = (per_sample - ce_sum) * 0.1f + commit;
    }
}

extern "C" void kernel_launch(void* const* d_in, const int* in_sizes, int n_in,
                              void* d_out, int out_size, void* d_ws, size_t ws_size,
                              hipStream_t stream)
{
    (void)in_sizes; (void)n_in; (void)out_size; (void)ws_size;

    const float* x     = (const float*)d_in[0];
    const float* W_in  = (const float*)d_in[1];
    const float* b_in  = (const float*)d_in[2];
    const float* W_out = (const float*)d_in[3];
    const float* b_out = (const float*)d_in[4];

    float* out     = (float*)d_out;
    float* out_idx = out + OUT_ELEMS;          // 8192 indices (as float)
    float* out_aux = out + OUT_ELEMS + NTOK;   // 1 scalar

    char* ws = (char*)d_ws;
    float* hist        = (float*)ws;                    // 64 KB
    float* pse_part    = (float*)(ws + 65536);          // 1 KB
    float* commit_part = (float*)(ws + 65536 + 1024);   // 1 KB

    // zero accumulators every launch (graph-capture safe, deterministic)
    hipMemsetAsync(d_ws, 0, 65536 + 2048, stream);

    k_proj_in<<<dim3(256), dim3(256), 0, stream>>>(
        x, W_in, b_in, out_idx, hist, pse_part, commit_part);
    k_proj_out<<<dim3(OUT_ELEMS / 256), dim3(256), 0, stream>>>(
        out_idx, W_out, b_out, out);
    k_finalize<<<dim3(1), dim3(256), 0, stream>>>(
        hist, pse_part, commit_part, out_aux);
}